// Round 9
// baseline (1978.831 us; speedup 1.0000x reference)
//
#include <hip/hip_runtime.h>

#define B_ 16
#define T_ 65536
#define H_ 64
#define DEPTH_ 4
#define CHUNK 64
#define NCH (T_ / CHUNK)   // 1024 chunks per sequence

typedef _Float16 f16;
typedef f16 f16x8 __attribute__((ext_vector_type(8)));
typedef float f32x4 __attribute__((ext_vector_type(4)));
typedef unsigned u32x4 __attribute__((ext_vector_type(4)));

#define MFMA(a, b, c) __builtin_amdgcn_mfma_f32_16x16x32_f16(a, b, c, 0, 0, 0)
// swizzled word index into hpk: row t (0..63), word k (0..63)
#define SWZ(t, k) ((t) * 64 + ((k) ^ (((t) & 7) << 2)))

union U4F8 { u32x4 u; f16x8 h; };

__device__ __forceinline__ f16x8 ldfrag(const f16* p) { return *(const f16x8*)p; }

// ---------- prep: weights to f16 hi/lo, diag fragments, decay tables, scalars ----------
// sc per layer (stride 320): [0]=a, [64]=Dv, [128]=bw(=g*Bm.Win), [192]=Dv*Win, [256]=Win
__global__ __launch_bounds__(256)
void prep(const float* __restrict__ Win, const float* __restrict__ nu,
          const float* __restrict__ ga, const float* __restrict__ Bm,
          const float* __restrict__ Cm, const float* __restrict__ Dv,
          const float* __restrict__ Wl,
          f16* __restrict__ BmH, f16* __restrict__ BmL,
          f16* __restrict__ CmH, f16* __restrict__ CmL,
          f16* __restrict__ WlH, float* __restrict__ atab, float* __restrict__ sc,
          f16* __restrict__ dvfH, f16* __restrict__ dvfL, f16* __restrict__ idf)
{
    const int tid = threadIdx.x;
    for (int l = 0; l < DEPTH_; ++l) {
        for (int idx = tid; idx < 4096; idx += 256) {
            int n = idx >> 6;
            float g = expf(ga[l * 64 + n]);
            float v = Bm[l * 4096 + idx] * g;
            f16 h = (f16)v;
            BmH[l * 4096 + idx] = h;
            BmL[l * 4096 + idx] = (f16)(v - (float)h);
            float cv = Cm[l * 4096 + idx];
            h = (f16)cv;
            CmH[l * 4096 + idx] = h;
            CmL[l * 4096 + idx] = (f16)(cv - (float)h);
            WlH[l * 4096 + idx] = (f16)Wl[l * 4096 + idx];
        }
        if (tid < 64) {
            int n = tid;
            float ex = expf(nu[l * 64 + n]);
            float a = expf(-ex);
            float g = expf(ga[l * 64 + n]);
            sc[l * 320 + n] = a;
            sc[l * 320 + 64 + n] = Dv[l * 64 + n];
            float bw = 0.f;
            for (int h2 = 0; h2 < 64; ++h2) bw += Bm[l * 4096 + n * 64 + h2] * Win[h2];
            sc[l * 320 + 128 + n] = bw * g;
            sc[l * 320 + 192 + n] = Dv[l * 64 + n] * Win[n];
            sc[l * 320 + 256 + n] = Win[n];
        }
        for (int idx = tid; idx < 4096; idx += 256) {
            int n = idx >> 6, j = idx & 63;
            float ex = expf(nu[l * 64 + n]);
            atab[l * 4096 + idx] = expf(-ex * (float)j);
        }
        // diag(Dv) B-fragments: dvf[nt][lane][8]
        for (int idx = tid; idx < 2048; idx += 256) {
            int nt = idx >> 9, lane = (idx >> 3) & 63, j = idx & 7;
            int l15 = lane & 15, lq = lane >> 4;
            int e = ((nt & 1) * 16 + l15) - lq * 8;
            int n = nt * 16 + l15;
            float val = (j == e) ? Dv[l * 64 + n] : 0.f;
            f16 h = (f16)val;
            dvfH[l * 2048 + idx] = h;
            dvfL[l * 2048 + idx] = (f16)(val - (float)h);
        }
    }
    // identity B-fragments (layer-independent)
    for (int idx = tid; idx < 2048; idx += 256) {
        int nt = idx >> 9, lane = (idx >> 3) & 63, j = idx & 7;
        int l15 = lane & 15, lq = lane >> 4;
        int e = ((nt & 1) * 16 + l15) - lq * 8;
        idf[idx] = (j == e) ? (f16)1.f : (f16)0.f;
    }
}

// ---------- raw carry for layer 0 (u_t = x_t*Win, rank-1); wave per chunk ----------
__global__ __launch_bounds__(256)
void carry_x(const float* __restrict__ x, const float* __restrict__ sc0,
             float* __restrict__ carry)
{
    const int blk = blockIdx.x;
    const int b = blk >> 8;
    const int tid = threadIdx.x;
    const int w = tid >> 6, lane = tid & 63;
    const int c = (blk & 255) * 4 + w;
    const float a  = sc0[lane];
    const float bw = sc0[128 + lane];
    float xval = x[(size_t)b * T_ + (size_t)c * CHUNK + lane];
    float s = 0.f;
    #pragma unroll
    for (int t = 0; t < 64; ++t) s = a * s + bw * __shfl(xval, t);
    carry[((size_t)b * NCH + c) * 64 + lane] = s;
}

// ---------- in-place exclusive decay-scan of per-chunk carries (batched loads) ----------
__global__ __launch_bounds__(256)
void scan_carry(const float* __restrict__ nu_log, float* __restrict__ carry)
{
    const int b = blockIdx.x;
    const int tid = threadIdx.x;
    const int n = tid & 63, q = tid >> 6;
    const float ex = expf(nu_log[n]);
    const float aL = expf(-ex * (float)CHUNK);
    float* cp = carry + (size_t)b * NCH * 64 + n;
    __shared__ float part[4][64];

    const int SEG = NCH / 4;            // 256
    const int base = q * SEG;
    float p = 0.f;
    float v[8], nv[8];
    #pragma unroll
    for (int j = 0; j < 8; ++j) v[j] = cp[(size_t)(base + j) * 64];
    for (int i0 = 0; i0 < SEG; i0 += 8) {
        if (i0 + 8 < SEG) {
            #pragma unroll
            for (int j = 0; j < 8; ++j) nv[j] = cp[(size_t)(base + i0 + 8 + j) * 64];
        }
        #pragma unroll
        for (int j = 0; j < 8; ++j) {
            float vv = v[j];
            cp[(size_t)(base + i0 + j) * 64] = p;
            p = aL * p + vv;
        }
        #pragma unroll
        for (int j = 0; j < 8; ++j) v[j] = nv[j];
    }
    part[q][n] = p;
    __syncthreads();
    if (q > 0) {
        const float aLS = expf(-ex * (float)(CHUNK * SEG));
        float inc = 0.f;
        for (int qq = 0; qq < q; ++qq) inc = inc * aLS + part[qq][n];
        for (int i0 = 0; i0 < SEG; i0 += 8) {
            float qs = inc;
            float o[8];
            #pragma unroll
            for (int j = 0; j < 8; ++j) { o[j] = cp[(size_t)(base + i0 + j) * 64]; }
            #pragma unroll
            for (int j = 0; j < 8; ++j) {
                cp[(size_t)(base + i0 + j) * 64] = o[j] + qs;
                qs *= aL;
            }
            inc = qs;
        }
    }
}

struct LPrep {
    const f16 *BmH, *BmL, *CmH, *CmL, *WlH;  // this layer (gamma folded into Bm)
    const float *av, *bw, *dwin, *win;       // this-layer scalars
    const f16 *dvfH, *dvfL, *idf;            // precomputed diag fragments
    const f16 *BmHn, *BmLn;                  // next-layer Bm (gamma folded)
    const float *atabn;                      // next-layer decay table a^j (64/n)
    const float *blin, *Wout;
};

// ---------- fused chunk kernel (CHUNK=64, 8 blocks/CU) ----------
template<int IN_X, int OUT_FINAL>
__global__ __launch_bounds__(256, 8)
void lru_fused(const float* __restrict__ x, f16* __restrict__ ubuf,
               LPrep P, float* __restrict__ carry, float* __restrict__ out)
{
    const int blk = blockIdx.x;
    const int b = blk >> 10, c = blk & (NCH - 1);
    const int t0 = c * CHUNK;
    const int tid = threadIdx.x;
    const int w = tid >> 6, lane = tid & 63;
    const int l15 = lane & 15, lq = lane >> 4;

    __shared__ float hpk[CHUNK * 64];   // 16 KB fp32: h_prev -> th -> staged o
    __shared__ float swv[4][64];
    __shared__ float red[4][64];

    f16* ug = ubuf + ((size_t)b * T_ + t0) * 64;
    const float* xg = x + (size_t)b * T_ + t0;

    // wave w owns rows [16w, 16w+16)
    const int trow = w * 16 + l15;

    // u A-frags (nontemporal, read-once)
    f16x8 ahu[2];
    if (!IN_X) {
        const f16* p = ug + (size_t)trow * 64;
        U4F8 r0, r1;
        r0.u = __builtin_nontemporal_load((const u32x4*)(p + lq * 8));
        r1.u = __builtin_nontemporal_load((const u32x4*)(p + 32 + lq * 8));
        ahu[0] = r0.h;
        ahu[1] = r1.h;
    }

    float av4[4], carr4[4];
    #pragma unroll
    for (int nt = 0; nt < 4; ++nt) {
        av4[nt] = P.av[nt * 16 + l15];
        carr4[nt] = carry[((size_t)b * NCH + c) * 64 + nt * 16 + l15];
    }

    float xv[4];
    if (IN_X) {
        #pragma unroll
        for (int r = 0; r < 4; ++r) xv[r] = xg[w * 16 + lq * 4 + r];
    }

    // ---- P1: Bu in registers (C-layout: t = 16w+4lq+r, n = nt*16+l15) ----
    f32x4 acc[4];
    if (IN_X) {
        #pragma unroll
        for (int nt = 0; nt < 4; ++nt) {
            float bwn = P.bw[nt * 16 + l15];
            #pragma unroll
            for (int r = 0; r < 4; ++r) acc[nt][r] = xv[r] * bwn;
        }
    } else {
        #pragma unroll
        for (int nt = 0; nt < 4; ++nt) {
            int n = nt * 16 + l15;
            f16x8 bh0 = ldfrag(P.BmH + n * 64 + lq * 8);
            f16x8 bh1 = ldfrag(P.BmH + n * 64 + 32 + lq * 8);
            f16x8 bl0 = ldfrag(P.BmL + n * 64 + lq * 8);
            f16x8 bl1 = ldfrag(P.BmL + n * 64 + 32 + lq * 8);
            f32x4 a4v = {0.f, 0.f, 0.f, 0.f};
            a4v = MFMA(ahu[0], bh0, a4v);
            a4v = MFMA(ahu[0], bl0, a4v);
            a4v = MFMA(ahu[1], bh1, a4v);
            a4v = MFMA(ahu[1], bl1, a4v);
            acc[nt] = a4v;
        }
    }

    // ---- P2: register scan (per n over 16 t of own tile) ----
    float Wb[4];
    #pragma unroll
    for (int nt = 0; nt < 4; ++nt) {
        float a = av4[nt], a2 = a * a, a4 = a2 * a2, a8 = a4 * a4;
        f32x4 xs = acc[nt];
        float L1 = a * xs[0] + xs[1];
        float L2 = a * L1 + xs[2];
        float Cv = a * L2 + xs[3];
        float u1 = __shfl_up(Cv, 16);
        float t1 = Cv + ((lq >= 1) ? a4 * u1 : 0.f);
        float u2 = __shfl_up(t1, 32);
        float Pv = t1 + ((lq >= 2) ? a8 * u2 : 0.f);
        float E = __shfl_up(Pv, 16);
        Wb[nt] = (lq == 0) ? 0.f : E;
        if (lq == 3) swv[w][nt * 16 + l15] = Pv;
    }
    __syncthreads();                       // barrier 1

    // ---- inc + h_prev writes (fp32, own rows) ----
    #pragma unroll
    for (int nt = 0; nt < 4; ++nt) {
        int n = nt * 16 + l15;
        float a = av4[nt], a2 = a * a, a4 = a2 * a2, a8 = a4 * a4, a16 = a8 * a8;
        float inc = carr4[nt];
        for (int ww = 0; ww < w; ++ww) inc = inc * a16 + swv[ww][n];
        float a4lq = 1.f;
        if (lq & 1) a4lq *= a4;
        if (lq & 2) a4lq *= a8;
        float s = Wb[nt] + a4lq * inc;
        #pragma unroll
        for (int r = 0; r < 4; ++r) {
            int t = 16 * w + 4 * lq + r;
            hpk[SWZ(t, n)] = s;           // h_{t-1}
            s = a * s + acc[nt][r];
        }
    }
    // no barrier: all subsequent hpk traffic is own-wave rows (in-wave DS order)

    // ---- P3: y = C.h_prev + Dv*u, tanh -> th (fp32, overwrite h) ----
    {
        int sw = (trow & 7) << 2;
        const float* hw = hpk + trow * 64;
        f16x8 ah[2], al[2];
        #pragma unroll
        for (int kk = 0; kk < 2; ++kk) {
            int kb = kk * 32 + lq * 8;
            float4 v0 = *(const float4*)(hw + (kb ^ sw));
            float4 v1 = *(const float4*)(hw + ((kb + 4) ^ sw));
            float vv[8] = {v0.x, v0.y, v0.z, v0.w, v1.x, v1.y, v1.z, v1.w};
            #pragma unroll
            for (int i = 0; i < 8; ++i) {
                f16 h = (f16)vv[i];
                ah[kk][i] = h;
                al[kk][i] = (f16)(vv[i] - (float)h);
            }
        }
        #pragma unroll
        for (int nt = 0; nt < 4; ++nt) {
            int n = nt * 16 + l15;
            f16x8 ch0 = ldfrag(P.CmH + n * 64 + lq * 8);
            f16x8 ch1 = ldfrag(P.CmH + n * 64 + 32 + lq * 8);
            f16x8 cl0 = ldfrag(P.CmL + n * 64 + lq * 8);
            f16x8 cl1 = ldfrag(P.CmL + n * 64 + 32 + lq * 8);
            f32x4 a4v = {0.f, 0.f, 0.f, 0.f};
            a4v = MFMA(ah[0], ch0, a4v);
            a4v = MFMA(al[0], ch0, a4v);
            a4v = MFMA(ah[0], cl0, a4v);
            a4v = MFMA(ah[1], ch1, a4v);
            a4v = MFMA(al[1], ch1, a4v);
            a4v = MFMA(ah[1], cl1, a4v);
            if (!IN_X) {
                f16x8 dfh = ldfrag(P.dvfH + (nt * 64 + lane) * 8);
                f16x8 dfl = ldfrag(P.dvfL + (nt * 64 + lane) * 8);
                a4v = MFMA(ahu[nt >> 1], dfh, a4v);
                a4v = MFMA(ahu[nt >> 1], dfl, a4v);
            }
            float dwin = IN_X ? P.dwin[n] : 0.f;
            #pragma unroll
            for (int r = 0; r < 4; ++r) {
                int t = 16 * w + lq * 4 + r;
                float y = a4v[r];
                if (IN_X) y += xv[r] * dwin;
                hpk[SWZ(t, n)] = y * rsqrtf(1.f + y * y);
            }
        }
    }

    // ---- P4: o = Wlin.th + blin + u; stage as f16 or final reduce ----
    f16* stg = (f16*)hpk;
    {
        int sw = (trow & 7) << 2;
        const float* hw = hpk + trow * 64;
        f16x8 t0f, t1f;
        #pragma unroll
        for (int kk = 0; kk < 2; ++kk) {
            int kb = kk * 32 + lq * 8;
            float4 v0 = *(const float4*)(hw + (kb ^ sw));
            float4 v1 = *(const float4*)(hw + ((kb + 4) ^ sw));
            float vv[8] = {v0.x, v0.y, v0.z, v0.w, v1.x, v1.y, v1.z, v1.w};
            #pragma unroll
            for (int i = 0; i < 8; ++i) {
                if (kk == 0) t0f[i] = (f16)vv[i]; else t1f[i] = (f16)vv[i];
            }
        }
        float val[4] = {0.f, 0.f, 0.f, 0.f};
        #pragma unroll
        for (int nt = 0; nt < 4; ++nt) {
            int n = nt * 16 + l15;
            f16x8 w0f = ldfrag(P.WlH + n * 64 + lq * 8);
            f16x8 w1f = ldfrag(P.WlH + n * 64 + 32 + lq * 8);
            f32x4 a4v = {0.f, 0.f, 0.f, 0.f};
            a4v = MFMA(t0f, w0f, a4v);
            a4v = MFMA(t1f, w1f, a4v);
            if (!IN_X) {
                f16x8 ifr = ldfrag(P.idf + (nt * 64 + lane) * 8);
                a4v = MFMA(ahu[nt >> 1], ifr, a4v);
            }
            float blj = P.blin[n];
            float wij = IN_X ? P.win[n] : 0.f;
            float woj = OUT_FINAL ? P.Wout[n] : 0.f;
            #pragma unroll
            for (int r = 0; r < 4; ++r) {
                int t = 16 * w + lq * 4 + r;
                float o = a4v[r] + blj;
                if (IN_X) o += xv[r] * wij;
                if (OUT_FINAL) {
                    val[r] += o * woj;
                } else {
                    int g = n >> 1;
                    int word = t * 64 + (((g & ~3) ^ ((t & 7) << 2)) | (g & 3));
                    stg[word * 2 + (n & 1)] = (f16)o;
                }
            }
        }
        if (OUT_FINAL) {
            #pragma unroll
            for (int r = 0; r < 4; ++r) {
                float p = val[r];
                p += __shfl_xor(p, 1);
                p += __shfl_xor(p, 2);
                p += __shfl_xor(p, 4);
                p += __shfl_xor(p, 8);
                if (l15 == 0) out[(size_t)b * T_ + t0 + 16 * w + lq * 4 + r] = p;
            }
        }
    }

    if (!OUT_FINAL) {
        // ---- coalesced nontemporal store of own 16 rows ----
        #pragma unroll
        for (int i = 0; i < 2; ++i) {
            int row = 16 * w + i * 8 + (lane >> 3);
            int gg = 4 * (lane & 7);
            int word = row * 64 + (gg ^ ((row & 7) << 2));
            u32x4 cv = *(const u32x4*)(hpk + word);
            __builtin_nontemporal_store(cv, (u32x4*)(ug + (size_t)row * 64 + 8 * (lane & 7)));
        }

        // ---- next-layer raw-carry GEMM from staged tile ----
        float partial[4] = {0.f, 0.f, 0.f, 0.f};
        {
            int msk = (trow & 7) << 2;
            U4F8 av0, av1;
            av0.u = *(const u32x4*)(hpk + trow * 64 + ((4 * lq) ^ msk));
            av1.u = *(const u32x4*)(hpk + trow * 64 + ((16 + 4 * lq) ^ msk));
            #pragma unroll
            for (int nt = 0; nt < 4; ++nt) {
                int n = nt * 16 + l15;
                f16x8 bh0 = ldfrag(P.BmHn + n * 64 + lq * 8);
                f16x8 bh1 = ldfrag(P.BmHn + n * 64 + 32 + lq * 8);
                f16x8 bl0 = ldfrag(P.BmLn + n * 64 + lq * 8);
                f16x8 bl1 = ldfrag(P.BmLn + n * 64 + 32 + lq * 8);
                f32x4 a4v = {0.f, 0.f, 0.f, 0.f};
                a4v = MFMA(av0.h, bh0, a4v);
                a4v = MFMA(av0.h, bl0, a4v);
                a4v = MFMA(av1.h, bh1, a4v);
                a4v = MFMA(av1.h, bl1, a4v);
                float4 dp = *(const float4*)(P.atabn + n * 64 + 60 - w * 16 - lq * 4);
                partial[nt] += a4v[0] * dp.w + a4v[1] * dp.z + a4v[2] * dp.y + a4v[3] * dp.x;
            }
        }
        #pragma unroll
        for (int nt = 0; nt < 4; ++nt) {
            float v = partial[nt];
            v += __shfl_xor(v, 16);
            v += __shfl_xor(v, 32);
            if (lq == 0) red[w][nt * 16 + l15] = v;
        }
        __syncthreads();                   // barrier 2
        if (w == 0)
            carry[((size_t)b * NCH + c) * 64 + lane] =
                red[0][lane] + red[1][lane] + red[2][lane] + red[3][lane];
    }
}

// ---------- host ----------
extern "C" void kernel_launch(void* const* d_in, const int* in_sizes, int n_in,
                              void* d_out, int out_size, void* d_ws, size_t ws_size,
                              hipStream_t stream)
{
    const float* x   = (const float*)d_in[0];
    const float* Win = (const float*)d_in[1];
    const float* nu  = (const float*)d_in[2];
    const float* ga  = (const float*)d_in[3];
    const float* Bm  = (const float*)d_in[4];
    const float* Cm  = (const float*)d_in[5];
    const float* Dv  = (const float*)d_in[6];
    const float* Wl  = (const float*)d_in[7];
    const float* bl  = (const float*)d_in[8];
    const float* Wo  = (const float*)d_in[9];
    float* out = (float*)d_out;

    char* p = (char*)d_ws;
    f16* ubuf = (f16*)p;            p += (size_t)B_ * T_ * 64 * sizeof(f16);
    float* carry = (float*)p;       p += (size_t)B_ * NCH * 64 * sizeof(float);
    f16* wBmH = (f16*)p;            p += 4 * 4096 * sizeof(f16);
    f16* wBmL = (f16*)p;            p += 4 * 4096 * sizeof(f16);
    f16* wCmH = (f16*)p;            p += 4 * 4096 * sizeof(f16);
    f16* wCmL = (f16*)p;            p += 4 * 4096 * sizeof(f16);
    f16* wWlH = (f16*)p;            p += 4 * 4096 * sizeof(f16);
    float* atab = (float*)p;        p += 4 * 4096 * sizeof(float);
    float* sc = (float*)p;          p += 4 * 320 * sizeof(float);
    f16* dvfH = (f16*)p;            p += 4 * 2048 * sizeof(f16);
    f16* dvfL = (f16*)p;            p += 4 * 2048 * sizeof(f16);
    f16* idf = (f16*)p;             p += 2048 * sizeof(f16);

    dim3 grid(B_ * NCH), blk256(256), gcx(B_ * NCH / 4), gscan(B_);

    prep<<<1, 256, 0, stream>>>(Win, nu, ga, Bm, Cm, Dv, Wl,
                                wBmH, wBmL, wCmH, wCmL, wWlH, atab, sc, dvfH, dvfL, idf);
    carry_x<<<gcx, blk256, 0, stream>>>(x, sc, carry);

    for (int l = 0; l < DEPTH_; ++l) {
        int ln = (l + 1 < DEPTH_) ? l + 1 : l;
        scan_carry<<<gscan, blk256, 0, stream>>>(nu + l * 64, carry);
        LPrep Pr;
        Pr.BmH = wBmH + l * 4096;  Pr.BmL = wBmL + l * 4096;
        Pr.CmH = wCmH + l * 4096;  Pr.CmL = wCmL + l * 4096;
        Pr.WlH = wWlH + l * 4096;
        Pr.av = sc + l * 320;
        Pr.bw = sc + l * 320 + 128; Pr.dwin = sc + l * 320 + 192;
        Pr.win = sc + l * 320 + 256;
        Pr.dvfH = dvfH + l * 2048;  Pr.dvfL = dvfL + l * 2048;  Pr.idf = idf;
        Pr.BmHn = wBmH + ln * 4096; Pr.BmLn = wBmL + ln * 4096;
        Pr.atabn = atab + ln * 4096;
        Pr.blin = bl + l * 64; Pr.Wout = Wo;
        if (l == 0)
            lru_fused<1, 0><<<grid, blk256, 0, stream>>>(x, ubuf, Pr, carry, out);
        else if (l == DEPTH_ - 1)
            lru_fused<0, 1><<<grid, blk256, 0, stream>>>(x, ubuf, Pr, carry, out);
        else
            lru_fused<0, 0><<<grid, blk256, 0, stream>>>(x, ubuf, Pr, carry, out);
    }
}

// Round 10
// 1863.075 us; speedup vs baseline: 1.0621x; 1.0621x over previous
//
#include <hip/hip_runtime.h>

#define B_ 16
#define T_ 65536
#define H_ 64
#define DEPTH_ 4
#define CHUNK 64
#define NCH (T_ / CHUNK)   // 1024 chunks per sequence

typedef _Float16 f16;
typedef f16 f16x8 __attribute__((ext_vector_type(8)));
typedef float f32x4 __attribute__((ext_vector_type(4)));
typedef unsigned u32x4 __attribute__((ext_vector_type(4)));

#define MFMA(a, b, c) __builtin_amdgcn_mfma_f32_16x16x32_f16(a, b, c, 0, 0, 0)
// swizzled word index into hpk: row t (0..63), word k (0..63)
#define SWZ(t, k) ((t) * 64 + ((k) ^ (((t) & 7) << 2)))

union U4F8 { u32x4 u; f16x8 h; };

__device__ __forceinline__ f16x8 ldfrag(const f16* p) { return *(const f16x8*)p; }

// ---------- prep: weights to f16 hi/lo, diag fragments, decay tables, scalars ----------
// sc per layer (stride 320): [0]=a, [64]=Dv, [128]=bw(=g*Bm.Win), [192]=Dv*Win, [256]=Win
__global__ __launch_bounds__(256)
void prep(const float* __restrict__ Win, const float* __restrict__ nu,
          const float* __restrict__ ga, const float* __restrict__ Bm,
          const float* __restrict__ Cm, const float* __restrict__ Dv,
          const float* __restrict__ Wl,
          f16* __restrict__ BmH, f16* __restrict__ BmL,
          f16* __restrict__ CmH, f16* __restrict__ CmL,
          f16* __restrict__ WlH, float* __restrict__ atab, float* __restrict__ sc,
          f16* __restrict__ dvfH, f16* __restrict__ dvfL, f16* __restrict__ idf)
{
    const int tid = threadIdx.x;
    for (int l = 0; l < DEPTH_; ++l) {
        for (int idx = tid; idx < 4096; idx += 256) {
            int n = idx >> 6;
            float g = expf(ga[l * 64 + n]);
            float v = Bm[l * 4096 + idx] * g;
            f16 h = (f16)v;
            BmH[l * 4096 + idx] = h;
            BmL[l * 4096 + idx] = (f16)(v - (float)h);
            float cv = Cm[l * 4096 + idx];
            h = (f16)cv;
            CmH[l * 4096 + idx] = h;
            CmL[l * 4096 + idx] = (f16)(cv - (float)h);
            WlH[l * 4096 + idx] = (f16)Wl[l * 4096 + idx];
        }
        if (tid < 64) {
            int n = tid;
            float ex = expf(nu[l * 64 + n]);
            float a = expf(-ex);
            float g = expf(ga[l * 64 + n]);
            sc[l * 320 + n] = a;
            sc[l * 320 + 64 + n] = Dv[l * 64 + n];
            float bw = 0.f;
            for (int h2 = 0; h2 < 64; ++h2) bw += Bm[l * 4096 + n * 64 + h2] * Win[h2];
            sc[l * 320 + 128 + n] = bw * g;
            sc[l * 320 + 192 + n] = Dv[l * 64 + n] * Win[n];
            sc[l * 320 + 256 + n] = Win[n];
        }
        for (int idx = tid; idx < 4096; idx += 256) {
            int n = idx >> 6, j = idx & 63;
            float ex = expf(nu[l * 64 + n]);
            atab[l * 4096 + idx] = expf(-ex * (float)j);
        }
        // diag(Dv) B-fragments: dvf[nt][lane][8]
        for (int idx = tid; idx < 2048; idx += 256) {
            int nt = idx >> 9, lane = (idx >> 3) & 63, j = idx & 7;
            int l15 = lane & 15, lq = lane >> 4;
            int e = ((nt & 1) * 16 + l15) - lq * 8;
            int n = nt * 16 + l15;
            float val = (j == e) ? Dv[l * 64 + n] : 0.f;
            f16 h = (f16)val;
            dvfH[l * 2048 + idx] = h;
            dvfL[l * 2048 + idx] = (f16)(val - (float)h);
        }
    }
    // identity B-fragments (layer-independent)
    for (int idx = tid; idx < 2048; idx += 256) {
        int nt = idx >> 9, lane = (idx >> 3) & 63, j = idx & 7;
        int l15 = lane & 15, lq = lane >> 4;
        int e = ((nt & 1) * 16 + l15) - lq * 8;
        idf[idx] = (j == e) ? (f16)1.f : (f16)0.f;
    }
}

// ---------- raw carry for layer 0 (u_t = x_t*Win, rank-1); wave per chunk ----------
__global__ __launch_bounds__(256)
void carry_x(const float* __restrict__ x, const float* __restrict__ sc0,
             float* __restrict__ carry)
{
    const int blk = blockIdx.x;
    const int b = blk >> 8;
    const int tid = threadIdx.x;
    const int w = tid >> 6, lane = tid & 63;
    const int c = (blk & 255) * 4 + w;
    const float a  = sc0[lane];
    const float bw = sc0[128 + lane];
    float xval = x[(size_t)b * T_ + (size_t)c * CHUNK + lane];
    float s = 0.f;
    #pragma unroll
    for (int t = 0; t < 64; ++t) s = a * s + bw * __shfl(xval, t);
    carry[((size_t)b * NCH + c) * 64 + lane] = s;
}

// ---------- in-place exclusive decay-scan of per-chunk carries (batched loads) ----------
__global__ __launch_bounds__(256)
void scan_carry(const float* __restrict__ nu_log, float* __restrict__ carry)
{
    const int b = blockIdx.x;
    const int tid = threadIdx.x;
    const int n = tid & 63, q = tid >> 6;
    const float ex = expf(nu_log[n]);
    const float aL = expf(-ex * (float)CHUNK);
    float* cp = carry + (size_t)b * NCH * 64 + n;
    __shared__ float part[4][64];

    const int SEG = NCH / 4;            // 256
    const int base = q * SEG;
    float p = 0.f;
    float v[8], nv[8];
    #pragma unroll
    for (int j = 0; j < 8; ++j) v[j] = cp[(size_t)(base + j) * 64];
    for (int i0 = 0; i0 < SEG; i0 += 8) {
        if (i0 + 8 < SEG) {
            #pragma unroll
            for (int j = 0; j < 8; ++j) nv[j] = cp[(size_t)(base + i0 + 8 + j) * 64];
        }
        #pragma unroll
        for (int j = 0; j < 8; ++j) {
            float vv = v[j];
            cp[(size_t)(base + i0 + j) * 64] = p;
            p = aL * p + vv;
        }
        #pragma unroll
        for (int j = 0; j < 8; ++j) v[j] = nv[j];
    }
    part[q][n] = p;
    __syncthreads();
    if (q > 0) {
        const float aLS = expf(-ex * (float)(CHUNK * SEG));
        float inc = 0.f;
        for (int qq = 0; qq < q; ++qq) inc = inc * aLS + part[qq][n];
        for (int i0 = 0; i0 < SEG; i0 += 8) {
            float qs = inc;
            float o[8];
            #pragma unroll
            for (int j = 0; j < 8; ++j) { o[j] = cp[(size_t)(base + i0 + j) * 64]; }
            #pragma unroll
            for (int j = 0; j < 8; ++j) {
                cp[(size_t)(base + i0 + j) * 64] = o[j] + qs;
                qs *= aL;
            }
            inc = qs;
        }
    }
}

struct LPrep {
    const f16 *BmH, *BmL, *CmH, *CmL, *WlH;  // this layer (gamma folded into Bm)
    const float *av, *bw, *dwin, *win;       // this-layer scalars
    const f16 *dvfH, *dvfL, *idf;            // precomputed diag fragments
    const f16 *BmHn, *BmLn;                  // next-layer Bm (gamma folded)
    const float *atabn;                      // next-layer decay table a^j (64/n)
    const float *blin, *Wout;
};

// ---------- fused chunk kernel (CHUNK=64) ----------
// __launch_bounds__(256,6): 85-VGPR budget (natural ~64, NO spill — (256,8)'s 64-VGPR
// budget forced scratch spills: +270 MB fetch/+545 MB write, the round-9 regression).
template<int IN_X, int OUT_FINAL>
__global__ __launch_bounds__(256, 6)
void lru_fused(const float* __restrict__ x, f16* __restrict__ ubuf,
               LPrep P, float* __restrict__ carry, float* __restrict__ out)
{
    const int blk = blockIdx.x;
    const int b = blk >> 10, c = blk & (NCH - 1);
    const int t0 = c * CHUNK;
    const int tid = threadIdx.x;
    const int w = tid >> 6, lane = tid & 63;
    const int l15 = lane & 15, lq = lane >> 4;

    __shared__ float hpk[CHUNK * 64];   // 16 KB fp32: h_prev -> th -> staged o
    __shared__ float swv[4][64];
    __shared__ float red[4][64];

    f16* ug = ubuf + ((size_t)b * T_ + t0) * 64;
    const float* xg = x + (size_t)b * T_ + t0;

    // wave w owns rows [16w, 16w+16)
    const int trow = w * 16 + l15;

    // u A-frags (nontemporal, read-once)
    f16x8 ahu[2];
    if (!IN_X) {
        const f16* p = ug + (size_t)trow * 64;
        U4F8 r0, r1;
        r0.u = __builtin_nontemporal_load((const u32x4*)(p + lq * 8));
        r1.u = __builtin_nontemporal_load((const u32x4*)(p + 32 + lq * 8));
        ahu[0] = r0.h;
        ahu[1] = r1.h;
    }

    float av4[4], carr4[4];
    #pragma unroll
    for (int nt = 0; nt < 4; ++nt) {
        av4[nt] = P.av[nt * 16 + l15];
        carr4[nt] = carry[((size_t)b * NCH + c) * 64 + nt * 16 + l15];
    }

    float xv[4];
    if (IN_X) {
        #pragma unroll
        for (int r = 0; r < 4; ++r) xv[r] = xg[w * 16 + lq * 4 + r];
    }

    // ---- P1: Bu in registers (C-layout: t = 16w+4lq+r, n = nt*16+l15) ----
    f32x4 acc[4];
    if (IN_X) {
        #pragma unroll
        for (int nt = 0; nt < 4; ++nt) {
            float bwn = P.bw[nt * 16 + l15];
            #pragma unroll
            for (int r = 0; r < 4; ++r) acc[nt][r] = xv[r] * bwn;
        }
    } else {
        #pragma unroll
        for (int nt = 0; nt < 4; ++nt) {
            int n = nt * 16 + l15;
            f16x8 bh0 = ldfrag(P.BmH + n * 64 + lq * 8);
            f16x8 bh1 = ldfrag(P.BmH + n * 64 + 32 + lq * 8);
            f16x8 bl0 = ldfrag(P.BmL + n * 64 + lq * 8);
            f16x8 bl1 = ldfrag(P.BmL + n * 64 + 32 + lq * 8);
            f32x4 a4v = {0.f, 0.f, 0.f, 0.f};
            a4v = MFMA(ahu[0], bh0, a4v);
            a4v = MFMA(ahu[0], bl0, a4v);
            a4v = MFMA(ahu[1], bh1, a4v);
            a4v = MFMA(ahu[1], bl1, a4v);
            acc[nt] = a4v;
        }
    }

    // ---- P2: register scan (per n over 16 t of own tile) ----
    float Wb[4];
    #pragma unroll
    for (int nt = 0; nt < 4; ++nt) {
        float a = av4[nt], a2 = a * a, a4 = a2 * a2, a8 = a4 * a4;
        f32x4 xs = acc[nt];
        float L1 = a * xs[0] + xs[1];
        float L2 = a * L1 + xs[2];
        float Cv = a * L2 + xs[3];
        float u1 = __shfl_up(Cv, 16);
        float t1 = Cv + ((lq >= 1) ? a4 * u1 : 0.f);
        float u2 = __shfl_up(t1, 32);
        float Pv = t1 + ((lq >= 2) ? a8 * u2 : 0.f);
        float E = __shfl_up(Pv, 16);
        Wb[nt] = (lq == 0) ? 0.f : E;
        if (lq == 3) swv[w][nt * 16 + l15] = Pv;
    }
    __syncthreads();                       // barrier 1

    // ---- inc + h_prev writes (fp32, own rows) ----
    #pragma unroll
    for (int nt = 0; nt < 4; ++nt) {
        int n = nt * 16 + l15;
        float a = av4[nt], a2 = a * a, a4 = a2 * a2, a8 = a4 * a4, a16 = a8 * a8;
        float inc = carr4[nt];
        for (int ww = 0; ww < w; ++ww) inc = inc * a16 + swv[ww][n];
        float a4lq = 1.f;
        if (lq & 1) a4lq *= a4;
        if (lq & 2) a4lq *= a8;
        float s = Wb[nt] + a4lq * inc;
        #pragma unroll
        for (int r = 0; r < 4; ++r) {
            int t = 16 * w + 4 * lq + r;
            hpk[SWZ(t, n)] = s;           // h_{t-1}
            s = a * s + acc[nt][r];
        }
    }
    // no barrier: all subsequent hpk traffic is own-wave rows (in-wave DS order)

    // ---- P3: y = C.h_prev + Dv*u, tanh -> th (fp32, overwrite h) ----
    {
        int sw = (trow & 7) << 2;
        const float* hw = hpk + trow * 64;
        f16x8 ah[2], al[2];
        #pragma unroll
        for (int kk = 0; kk < 2; ++kk) {
            int kb = kk * 32 + lq * 8;
            float4 v0 = *(const float4*)(hw + (kb ^ sw));
            float4 v1 = *(const float4*)(hw + ((kb + 4) ^ sw));
            float vv[8] = {v0.x, v0.y, v0.z, v0.w, v1.x, v1.y, v1.z, v1.w};
            #pragma unroll
            for (int i = 0; i < 8; ++i) {
                f16 h = (f16)vv[i];
                ah[kk][i] = h;
                al[kk][i] = (f16)(vv[i] - (float)h);
            }
        }
        #pragma unroll
        for (int nt = 0; nt < 4; ++nt) {
            int n = nt * 16 + l15;
            f16x8 ch0 = ldfrag(P.CmH + n * 64 + lq * 8);
            f16x8 ch1 = ldfrag(P.CmH + n * 64 + 32 + lq * 8);
            f16x8 cl0 = ldfrag(P.CmL + n * 64 + lq * 8);
            f16x8 cl1 = ldfrag(P.CmL + n * 64 + 32 + lq * 8);
            f32x4 a4v = {0.f, 0.f, 0.f, 0.f};
            a4v = MFMA(ah[0], ch0, a4v);
            a4v = MFMA(al[0], ch0, a4v);
            a4v = MFMA(ah[0], cl0, a4v);
            a4v = MFMA(ah[1], ch1, a4v);
            a4v = MFMA(al[1], ch1, a4v);
            a4v = MFMA(ah[1], cl1, a4v);
            if (!IN_X) {
                f16x8 dfh = ldfrag(P.dvfH + (nt * 64 + lane) * 8);
                f16x8 dfl = ldfrag(P.dvfL + (nt * 64 + lane) * 8);
                a4v = MFMA(ahu[nt >> 1], dfh, a4v);
                a4v = MFMA(ahu[nt >> 1], dfl, a4v);
            }
            float dwin = IN_X ? P.dwin[n] : 0.f;
            #pragma unroll
            for (int r = 0; r < 4; ++r) {
                int t = 16 * w + lq * 4 + r;
                float y = a4v[r];
                if (IN_X) y += xv[r] * dwin;
                hpk[SWZ(t, n)] = y * rsqrtf(1.f + y * y);
            }
        }
    }

    // ---- P4: o = Wlin.th + blin + u; stage as f16 or final reduce ----
    f16* stg = (f16*)hpk;
    {
        int sw = (trow & 7) << 2;
        const float* hw = hpk + trow * 64;
        f16x8 t0f, t1f;
        #pragma unroll
        for (int kk = 0; kk < 2; ++kk) {
            int kb = kk * 32 + lq * 8;
            float4 v0 = *(const float4*)(hw + (kb ^ sw));
            float4 v1 = *(const float4*)(hw + ((kb + 4) ^ sw));
            float vv[8] = {v0.x, v0.y, v0.z, v0.w, v1.x, v1.y, v1.z, v1.w};
            #pragma unroll
            for (int i = 0; i < 8; ++i) {
                if (kk == 0) t0f[i] = (f16)vv[i]; else t1f[i] = (f16)vv[i];
            }
        }
        float val[4] = {0.f, 0.f, 0.f, 0.f};
        #pragma unroll
        for (int nt = 0; nt < 4; ++nt) {
            int n = nt * 16 + l15;
            f16x8 w0f = ldfrag(P.WlH + n * 64 + lq * 8);
            f16x8 w1f = ldfrag(P.WlH + n * 64 + 32 + lq * 8);
            f32x4 a4v = {0.f, 0.f, 0.f, 0.f};
            a4v = MFMA(t0f, w0f, a4v);
            a4v = MFMA(t1f, w1f, a4v);
            if (!IN_X) {
                f16x8 ifr = ldfrag(P.idf + (nt * 64 + lane) * 8);
                a4v = MFMA(ahu[nt >> 1], ifr, a4v);
            }
            float blj = P.blin[n];
            float wij = IN_X ? P.win[n] : 0.f;
            float woj = OUT_FINAL ? P.Wout[n] : 0.f;
            #pragma unroll
            for (int r = 0; r < 4; ++r) {
                int t = 16 * w + lq * 4 + r;
                float o = a4v[r] + blj;
                if (IN_X) o += xv[r] * wij;
                if (OUT_FINAL) {
                    val[r] += o * woj;
                } else {
                    int g = n >> 1;
                    int word = t * 64 + (((g & ~3) ^ ((t & 7) << 2)) | (g & 3));
                    stg[word * 2 + (n & 1)] = (f16)o;
                }
            }
        }
        if (OUT_FINAL) {
            #pragma unroll
            for (int r = 0; r < 4; ++r) {
                float p = val[r];
                p += __shfl_xor(p, 1);
                p += __shfl_xor(p, 2);
                p += __shfl_xor(p, 4);
                p += __shfl_xor(p, 8);
                if (l15 == 0) out[(size_t)b * T_ + t0 + 16 * w + lq * 4 + r] = p;
            }
        }
    }

    if (!OUT_FINAL) {
        // ---- coalesced nontemporal store of own 16 rows ----
        #pragma unroll
        for (int i = 0; i < 2; ++i) {
            int row = 16 * w + i * 8 + (lane >> 3);
            int gg = 4 * (lane & 7);
            int word = row * 64 + (gg ^ ((row & 7) << 2));
            u32x4 cv = *(const u32x4*)(hpk + word);
            __builtin_nontemporal_store(cv, (u32x4*)(ug + (size_t)row * 64 + 8 * (lane & 7)));
        }

        // ---- next-layer raw-carry GEMM from staged tile ----
        float partial[4] = {0.f, 0.f, 0.f, 0.f};
        {
            int msk = (trow & 7) << 2;
            U4F8 av0, av1;
            av0.u = *(const u32x4*)(hpk + trow * 64 + ((4 * lq) ^ msk));
            av1.u = *(const u32x4*)(hpk + trow * 64 + ((16 + 4 * lq) ^ msk));
            #pragma unroll
            for (int nt = 0; nt < 4; ++nt) {
                int n = nt * 16 + l15;
                f16x8 bh0 = ldfrag(P.BmHn + n * 64 + lq * 8);
                f16x8 bh1 = ldfrag(P.BmHn + n * 64 + 32 + lq * 8);
                f16x8 bl0 = ldfrag(P.BmLn + n * 64 + lq * 8);
                f16x8 bl1 = ldfrag(P.BmLn + n * 64 + 32 + lq * 8);
                f32x4 a4v = {0.f, 0.f, 0.f, 0.f};
                a4v = MFMA(av0.h, bh0, a4v);
                a4v = MFMA(av0.h, bl0, a4v);
                a4v = MFMA(av1.h, bh1, a4v);
                a4v = MFMA(av1.h, bl1, a4v);
                float4 dp = *(const float4*)(P.atabn + n * 64 + 60 - w * 16 - lq * 4);
                partial[nt] += a4v[0] * dp.w + a4v[1] * dp.z + a4v[2] * dp.y + a4v[3] * dp.x;
            }
        }
        #pragma unroll
        for (int nt = 0; nt < 4; ++nt) {
            float v = partial[nt];
            v += __shfl_xor(v, 16);
            v += __shfl_xor(v, 32);
            if (lq == 0) red[w][nt * 16 + l15] = v;
        }
        __syncthreads();                   // barrier 2
        if (w == 0)
            carry[((size_t)b * NCH + c) * 64 + lane] =
                red[0][lane] + red[1][lane] + red[2][lane] + red[3][lane];
    }
}

// ---------- host ----------
extern "C" void kernel_launch(void* const* d_in, const int* in_sizes, int n_in,
                              void* d_out, int out_size, void* d_ws, size_t ws_size,
                              hipStream_t stream)
{
    const float* x   = (const float*)d_in[0];
    const float* Win = (const float*)d_in[1];
    const float* nu  = (const float*)d_in[2];
    const float* ga  = (const float*)d_in[3];
    const float* Bm  = (const float*)d_in[4];
    const float* Cm  = (const float*)d_in[5];
    const float* Dv  = (const float*)d_in[6];
    const float* Wl  = (const float*)d_in[7];
    const float* bl  = (const float*)d_in[8];
    const float* Wo  = (const float*)d_in[9];
    float* out = (float*)d_out;

    char* p = (char*)d_ws;
    f16* ubuf = (f16*)p;            p += (size_t)B_ * T_ * 64 * sizeof(f16);
    float* carry = (float*)p;       p += (size_t)B_ * NCH * 64 * sizeof(float);
    f16* wBmH = (f16*)p;            p += 4 * 4096 * sizeof(f16);
    f16* wBmL = (f16*)p;            p += 4 * 4096 * sizeof(f16);
    f16* wCmH = (f16*)p;            p += 4 * 4096 * sizeof(f16);
    f16* wCmL = (f16*)p;            p += 4 * 4096 * sizeof(f16);
    f16* wWlH = (f16*)p;            p += 4 * 4096 * sizeof(f16);
    float* atab = (float*)p;        p += 4 * 4096 * sizeof(float);
    float* sc = (float*)p;          p += 4 * 320 * sizeof(float);
    f16* dvfH = (f16*)p;            p += 4 * 2048 * sizeof(f16);
    f16* dvfL = (f16*)p;            p += 4 * 2048 * sizeof(f16);
    f16* idf = (f16*)p;             p += 2048 * sizeof(f16);

    dim3 grid(B_ * NCH), blk256(256), gcx(B_ * NCH / 4), gscan(B_);

    prep<<<1, 256, 0, stream>>>(Win, nu, ga, Bm, Cm, Dv, Wl,
                                wBmH, wBmL, wCmH, wCmL, wWlH, atab, sc, dvfH, dvfL, idf);
    carry_x<<<gcx, blk256, 0, stream>>>(x, sc, carry);

    for (int l = 0; l < DEPTH_; ++l) {
        int ln = (l + 1 < DEPTH_) ? l + 1 : l;
        scan_carry<<<gscan, blk256, 0, stream>>>(nu + l * 64, carry);
        LPrep Pr;
        Pr.BmH = wBmH + l * 4096;  Pr.BmL = wBmL + l * 4096;
        Pr.CmH = wCmH + l * 4096;  Pr.CmL = wCmL + l * 4096;
        Pr.WlH = wWlH + l * 4096;
        Pr.av = sc + l * 320;
        Pr.bw = sc + l * 320 + 128; Pr.dwin = sc + l * 320 + 192;
        Pr.win = sc + l * 320 + 256;
        Pr.dvfH = dvfH + l * 2048;  Pr.dvfL = dvfL + l * 2048;  Pr.idf = idf;
        Pr.BmHn = wBmH + ln * 4096; Pr.BmLn = wBmL + ln * 4096;
        Pr.atabn = atab + ln * 4096;
        Pr.blin = bl + l * 64; Pr.Wout = Wo;
        if (l == 0)
            lru_fused<1, 0><<<grid, blk256, 0, stream>>>(x, ubuf, Pr, carry, out);
        else if (l == DEPTH_ - 1)
            lru_fused<0, 1><<<grid, blk256, 0, stream>>>(x, ubuf, Pr, carry, out);
        else
            lru_fused<0, 0><<<grid, blk256, 0, stream>>>(x, ubuf, Pr, carry, out);
    }
}

// Round 11
// 1795.659 us; speedup vs baseline: 1.1020x; 1.0375x over previous
//
#include <hip/hip_runtime.h>

#define B_ 16
#define T_ 65536
#define H_ 64
#define DEPTH_ 4
#define CHUNK 64
#define NCH (T_ / CHUNK)   // 1024 chunks per sequence

typedef _Float16 f16;
typedef f16 f16x8 __attribute__((ext_vector_type(8)));
typedef float f32x4 __attribute__((ext_vector_type(4)));
typedef unsigned u32x4 __attribute__((ext_vector_type(4)));

#define MFMA(a, b, c) __builtin_amdgcn_mfma_f32_16x16x32_f16(a, b, c, 0, 0, 0)
// swizzled word index into hpk: row t (0..63), word k (0..63)
#define SWZ(t, k) ((t) * 64 + ((k) ^ (((t) & 7) << 2)))

union U4F8 { u32x4 u; f16x8 h; };

__device__ __forceinline__ f16x8 ldfrag(const f16* p) { return *(const f16x8*)p; }

// ---------- prep: weights to f16 hi/lo, diag fragments, decay tables, scalars ----------
// sc per layer (stride 320): [0]=a, [64]=Dv, [128]=bw(=g*Bm.Win), [192]=Dv*Win, [256]=Win
__global__ __launch_bounds__(256)
void prep(const float* __restrict__ Win, const float* __restrict__ nu,
          const float* __restrict__ ga, const float* __restrict__ Bm,
          const float* __restrict__ Cm, const float* __restrict__ Dv,
          const float* __restrict__ Wl,
          f16* __restrict__ BmH, f16* __restrict__ BmL,
          f16* __restrict__ CmH, f16* __restrict__ CmL,
          f16* __restrict__ WlH, float* __restrict__ atab, float* __restrict__ sc,
          f16* __restrict__ dvfH, f16* __restrict__ dvfL, f16* __restrict__ idf)
{
    const int tid = threadIdx.x;
    for (int l = 0; l < DEPTH_; ++l) {
        for (int idx = tid; idx < 4096; idx += 256) {
            int n = idx >> 6;
            float g = expf(ga[l * 64 + n]);
            float v = Bm[l * 4096 + idx] * g;
            f16 h = (f16)v;
            BmH[l * 4096 + idx] = h;
            BmL[l * 4096 + idx] = (f16)(v - (float)h);
            float cv = Cm[l * 4096 + idx];
            h = (f16)cv;
            CmH[l * 4096 + idx] = h;
            CmL[l * 4096 + idx] = (f16)(cv - (float)h);
            WlH[l * 4096 + idx] = (f16)Wl[l * 4096 + idx];
        }
        if (tid < 64) {
            int n = tid;
            float ex = expf(nu[l * 64 + n]);
            float a = expf(-ex);
            float g = expf(ga[l * 64 + n]);
            sc[l * 320 + n] = a;
            sc[l * 320 + 64 + n] = Dv[l * 64 + n];
            float bw = 0.f;
            for (int h2 = 0; h2 < 64; ++h2) bw += Bm[l * 4096 + n * 64 + h2] * Win[h2];
            sc[l * 320 + 128 + n] = bw * g;
            sc[l * 320 + 192 + n] = Dv[l * 64 + n] * Win[n];
            sc[l * 320 + 256 + n] = Win[n];
        }
        for (int idx = tid; idx < 4096; idx += 256) {
            int n = idx >> 6, j = idx & 63;
            float ex = expf(nu[l * 64 + n]);
            atab[l * 4096 + idx] = expf(-ex * (float)j);
        }
        // diag(Dv) B-fragments: dvf[nt][lane][8]
        for (int idx = tid; idx < 2048; idx += 256) {
            int nt = idx >> 9, lane = (idx >> 3) & 63, j = idx & 7;
            int l15 = lane & 15, lq = lane >> 4;
            int e = ((nt & 1) * 16 + l15) - lq * 8;
            int n = nt * 16 + l15;
            float val = (j == e) ? Dv[l * 64 + n] : 0.f;
            f16 h = (f16)val;
            dvfH[l * 2048 + idx] = h;
            dvfL[l * 2048 + idx] = (f16)(val - (float)h);
        }
    }
    // identity B-fragments (layer-independent)
    for (int idx = tid; idx < 2048; idx += 256) {
        int nt = idx >> 9, lane = (idx >> 3) & 63, j = idx & 7;
        int l15 = lane & 15, lq = lane >> 4;
        int e = ((nt & 1) * 16 + l15) - lq * 8;
        idf[idx] = (j == e) ? (f16)1.f : (f16)0.f;
    }
}

// ---------- raw carry for layer 0 (u_t = x_t*Win, rank-1); wave per chunk ----------
__global__ __launch_bounds__(256)
void carry_x(const float* __restrict__ x, const float* __restrict__ sc0,
             float* __restrict__ carry)
{
    const int blk = blockIdx.x;
    const int b = blk >> 8;
    const int tid = threadIdx.x;
    const int w = tid >> 6, lane = tid & 63;
    const int c = (blk & 255) * 4 + w;
    const float a  = sc0[lane];
    const float bw = sc0[128 + lane];
    float xval = x[(size_t)b * T_ + (size_t)c * CHUNK + lane];
    float s = 0.f;
    #pragma unroll
    for (int t = 0; t < 64; ++t) s = a * s + bw * __shfl(xval, t);
    carry[((size_t)b * NCH + c) * 64 + lane] = s;
}

// ---------- in-place exclusive decay-scan of per-chunk carries (batched loads) ----------
__global__ __launch_bounds__(256)
void scan_carry(const float* __restrict__ nu_log, float* __restrict__ carry)
{
    const int b = blockIdx.x;
    const int tid = threadIdx.x;
    const int n = tid & 63, q = tid >> 6;
    const float ex = expf(nu_log[n]);
    const float aL = expf(-ex * (float)CHUNK);
    float* cp = carry + (size_t)b * NCH * 64 + n;
    __shared__ float part[4][64];

    const int SEG = NCH / 4;            // 256
    const int base = q * SEG;
    float p = 0.f;
    float v[8], nv[8];
    #pragma unroll
    for (int j = 0; j < 8; ++j) v[j] = cp[(size_t)(base + j) * 64];
    for (int i0 = 0; i0 < SEG; i0 += 8) {
        if (i0 + 8 < SEG) {
            #pragma unroll
            for (int j = 0; j < 8; ++j) nv[j] = cp[(size_t)(base + i0 + 8 + j) * 64];
        }
        #pragma unroll
        for (int j = 0; j < 8; ++j) {
            float vv = v[j];
            cp[(size_t)(base + i0 + j) * 64] = p;
            p = aL * p + vv;
        }
        #pragma unroll
        for (int j = 0; j < 8; ++j) v[j] = nv[j];
    }
    part[q][n] = p;
    __syncthreads();
    if (q > 0) {
        const float aLS = expf(-ex * (float)(CHUNK * SEG));
        float inc = 0.f;
        for (int qq = 0; qq < q; ++qq) inc = inc * aLS + part[qq][n];
        for (int i0 = 0; i0 < SEG; i0 += 8) {
            float qs = inc;
            float o[8];
            #pragma unroll
            for (int j = 0; j < 8; ++j) { o[j] = cp[(size_t)(base + i0 + j) * 64]; }
            #pragma unroll
            for (int j = 0; j < 8; ++j) {
                cp[(size_t)(base + i0 + j) * 64] = o[j] + qs;
                qs *= aL;
            }
            inc = qs;
        }
    }
}

struct LPrep {
    const f16 *BmH, *BmL, *CmH, *CmL, *WlH;  // this layer (gamma folded into Bm)
    const float *av, *bw, *dwin, *win;       // this-layer scalars
    const f16 *dvfH, *dvfL, *idf;            // precomputed diag fragments
    const f16 *BmHn, *BmLn;                  // next-layer Bm (gamma folded)
    const float *atabn;                      // next-layer decay table a^j (64/n)
    const float *blin, *Wout;
};

// ---------- fused chunk kernel (CHUNK=64) ----------
// __launch_bounds__(256,4): compiler VGPR budget = 64 (empirical: budget=256/minwaves;
// 6→40 and 8→32 both SPILLED ~300MB scratch to HBM — rounds 9/10 regressions).
// At VGPR=64 the HW still allows 8 waves/SIMD; LDS 18.4KB allows 8 blocks/CU,
// so actual occupancy is LDS/VGPR-HW-limited (~8 blocks), not the declared 4.
template<int IN_X, int OUT_FINAL>
__global__ __launch_bounds__(256, 4)
void lru_fused(const float* __restrict__ x, f16* __restrict__ ubuf,
               LPrep P, float* __restrict__ carry, float* __restrict__ out)
{
    const int blk = blockIdx.x;
    const int b = blk >> 10, c = blk & (NCH - 1);
    const int t0 = c * CHUNK;
    const int tid = threadIdx.x;
    const int w = tid >> 6, lane = tid & 63;
    const int l15 = lane & 15, lq = lane >> 4;

    __shared__ float hpk[CHUNK * 64];   // 16 KB fp32: h_prev -> th -> staged o
    __shared__ float swv[4][64];
    __shared__ float red[4][64];

    f16* ug = ubuf + ((size_t)b * T_ + t0) * 64;
    const float* xg = x + (size_t)b * T_ + t0;

    // wave w owns rows [16w, 16w+16)
    const int trow = w * 16 + l15;

    // u A-frags (nontemporal, read-once)
    f16x8 ahu[2];
    if (!IN_X) {
        const f16* p = ug + (size_t)trow * 64;
        U4F8 r0, r1;
        r0.u = __builtin_nontemporal_load((const u32x4*)(p + lq * 8));
        r1.u = __builtin_nontemporal_load((const u32x4*)(p + 32 + lq * 8));
        ahu[0] = r0.h;
        ahu[1] = r1.h;
    }

    float av4[4], carr4[4];
    #pragma unroll
    for (int nt = 0; nt < 4; ++nt) {
        av4[nt] = P.av[nt * 16 + l15];
        carr4[nt] = carry[((size_t)b * NCH + c) * 64 + nt * 16 + l15];
    }

    float xv[4];
    if (IN_X) {
        #pragma unroll
        for (int r = 0; r < 4; ++r) xv[r] = xg[w * 16 + lq * 4 + r];
    }

    // ---- P1: Bu in registers (C-layout: t = 16w+4lq+r, n = nt*16+l15) ----
    f32x4 acc[4];
    if (IN_X) {
        #pragma unroll
        for (int nt = 0; nt < 4; ++nt) {
            float bwn = P.bw[nt * 16 + l15];
            #pragma unroll
            for (int r = 0; r < 4; ++r) acc[nt][r] = xv[r] * bwn;
        }
    } else {
        #pragma unroll
        for (int nt = 0; nt < 4; ++nt) {
            int n = nt * 16 + l15;
            f16x8 bh0 = ldfrag(P.BmH + n * 64 + lq * 8);
            f16x8 bh1 = ldfrag(P.BmH + n * 64 + 32 + lq * 8);
            f16x8 bl0 = ldfrag(P.BmL + n * 64 + lq * 8);
            f16x8 bl1 = ldfrag(P.BmL + n * 64 + 32 + lq * 8);
            f32x4 a4v = {0.f, 0.f, 0.f, 0.f};
            a4v = MFMA(ahu[0], bh0, a4v);
            a4v = MFMA(ahu[0], bl0, a4v);
            a4v = MFMA(ahu[1], bh1, a4v);
            a4v = MFMA(ahu[1], bl1, a4v);
            acc[nt] = a4v;
        }
    }

    // ---- P2: register scan (per n over 16 t of own tile) ----
    float Wb[4];
    #pragma unroll
    for (int nt = 0; nt < 4; ++nt) {
        float a = av4[nt], a2 = a * a, a4 = a2 * a2, a8 = a4 * a4;
        f32x4 xs = acc[nt];
        float L1 = a * xs[0] + xs[1];
        float L2 = a * L1 + xs[2];
        float Cv = a * L2 + xs[3];
        float u1 = __shfl_up(Cv, 16);
        float t1 = Cv + ((lq >= 1) ? a4 * u1 : 0.f);
        float u2 = __shfl_up(t1, 32);
        float Pv = t1 + ((lq >= 2) ? a8 * u2 : 0.f);
        float E = __shfl_up(Pv, 16);
        Wb[nt] = (lq == 0) ? 0.f : E;
        if (lq == 3) swv[w][nt * 16 + l15] = Pv;
    }
    __syncthreads();                       // barrier 1

    // ---- inc + h_prev writes (fp32, own rows) ----
    #pragma unroll
    for (int nt = 0; nt < 4; ++nt) {
        int n = nt * 16 + l15;
        float a = av4[nt], a2 = a * a, a4 = a2 * a2, a8 = a4 * a4, a16 = a8 * a8;
        float inc = carr4[nt];
        for (int ww = 0; ww < w; ++ww) inc = inc * a16 + swv[ww][n];
        float a4lq = 1.f;
        if (lq & 1) a4lq *= a4;
        if (lq & 2) a4lq *= a8;
        float s = Wb[nt] + a4lq * inc;
        #pragma unroll
        for (int r = 0; r < 4; ++r) {
            int t = 16 * w + 4 * lq + r;
            hpk[SWZ(t, n)] = s;           // h_{t-1}
            s = a * s + acc[nt][r];
        }
    }
    // no barrier: all subsequent hpk traffic is own-wave rows (in-wave DS order)

    // ---- P3: y = C.h_prev + Dv*u, tanh -> th (fp32, overwrite h) ----
    {
        int sw = (trow & 7) << 2;
        const float* hw = hpk + trow * 64;
        f16x8 ah[2], al[2];
        #pragma unroll
        for (int kk = 0; kk < 2; ++kk) {
            int kb = kk * 32 + lq * 8;
            float4 v0 = *(const float4*)(hw + (kb ^ sw));
            float4 v1 = *(const float4*)(hw + ((kb + 4) ^ sw));
            float vv[8] = {v0.x, v0.y, v0.z, v0.w, v1.x, v1.y, v1.z, v1.w};
            #pragma unroll
            for (int i = 0; i < 8; ++i) {
                f16 h = (f16)vv[i];
                ah[kk][i] = h;
                al[kk][i] = (f16)(vv[i] - (float)h);
            }
        }
        #pragma unroll
        for (int nt = 0; nt < 4; ++nt) {
            int n = nt * 16 + l15;
            f16x8 ch0 = ldfrag(P.CmH + n * 64 + lq * 8);
            f16x8 ch1 = ldfrag(P.CmH + n * 64 + 32 + lq * 8);
            f16x8 cl0 = ldfrag(P.CmL + n * 64 + lq * 8);
            f16x8 cl1 = ldfrag(P.CmL + n * 64 + 32 + lq * 8);
            f32x4 a4v = {0.f, 0.f, 0.f, 0.f};
            a4v = MFMA(ah[0], ch0, a4v);
            a4v = MFMA(al[0], ch0, a4v);
            a4v = MFMA(ah[0], cl0, a4v);
            a4v = MFMA(ah[1], ch1, a4v);
            a4v = MFMA(al[1], ch1, a4v);
            a4v = MFMA(ah[1], cl1, a4v);
            if (!IN_X) {
                f16x8 dfh = ldfrag(P.dvfH + (nt * 64 + lane) * 8);
                f16x8 dfl = ldfrag(P.dvfL + (nt * 64 + lane) * 8);
                a4v = MFMA(ahu[nt >> 1], dfh, a4v);
                a4v = MFMA(ahu[nt >> 1], dfl, a4v);
            }
            float dwin = IN_X ? P.dwin[n] : 0.f;
            #pragma unroll
            for (int r = 0; r < 4; ++r) {
                int t = 16 * w + lq * 4 + r;
                float y = a4v[r];
                if (IN_X) y += xv[r] * dwin;
                hpk[SWZ(t, n)] = y * rsqrtf(1.f + y * y);
            }
        }
    }

    // ---- P4: o = Wlin.th + blin + u; stage as f16 or final reduce ----
    f16* stg = (f16*)hpk;
    {
        int sw = (trow & 7) << 2;
        const float* hw = hpk + trow * 64;
        f16x8 t0f, t1f;
        #pragma unroll
        for (int kk = 0; kk < 2; ++kk) {
            int kb = kk * 32 + lq * 8;
            float4 v0 = *(const float4*)(hw + (kb ^ sw));
            float4 v1 = *(const float4*)(hw + ((kb + 4) ^ sw));
            float vv[8] = {v0.x, v0.y, v0.z, v0.w, v1.x, v1.y, v1.z, v1.w};
            #pragma unroll
            for (int i = 0; i < 8; ++i) {
                if (kk == 0) t0f[i] = (f16)vv[i]; else t1f[i] = (f16)vv[i];
            }
        }
        float val[4] = {0.f, 0.f, 0.f, 0.f};
        #pragma unroll
        for (int nt = 0; nt < 4; ++nt) {
            int n = nt * 16 + l15;
            f16x8 w0f = ldfrag(P.WlH + n * 64 + lq * 8);
            f16x8 w1f = ldfrag(P.WlH + n * 64 + 32 + lq * 8);
            f32x4 a4v = {0.f, 0.f, 0.f, 0.f};
            a4v = MFMA(t0f, w0f, a4v);
            a4v = MFMA(t1f, w1f, a4v);
            if (!IN_X) {
                f16x8 ifr = ldfrag(P.idf + (nt * 64 + lane) * 8);
                a4v = MFMA(ahu[nt >> 1], ifr, a4v);
            }
            float blj = P.blin[n];
            float wij = IN_X ? P.win[n] : 0.f;
            float woj = OUT_FINAL ? P.Wout[n] : 0.f;
            #pragma unroll
            for (int r = 0; r < 4; ++r) {
                int t = 16 * w + lq * 4 + r;
                float o = a4v[r] + blj;
                if (IN_X) o += xv[r] * wij;
                if (OUT_FINAL) {
                    val[r] += o * woj;
                } else {
                    int g = n >> 1;
                    int word = t * 64 + (((g & ~3) ^ ((t & 7) << 2)) | (g & 3));
                    stg[word * 2 + (n & 1)] = (f16)o;
                }
            }
        }
        if (OUT_FINAL) {
            #pragma unroll
            for (int r = 0; r < 4; ++r) {
                float p = val[r];
                p += __shfl_xor(p, 1);
                p += __shfl_xor(p, 2);
                p += __shfl_xor(p, 4);
                p += __shfl_xor(p, 8);
                if (l15 == 0) out[(size_t)b * T_ + t0 + 16 * w + lq * 4 + r] = p;
            }
        }
    }

    if (!OUT_FINAL) {
        // ---- coalesced nontemporal store of own 16 rows ----
        #pragma unroll
        for (int i = 0; i < 2; ++i) {
            int row = 16 * w + i * 8 + (lane >> 3);
            int gg = 4 * (lane & 7);
            int word = row * 64 + (gg ^ ((row & 7) << 2));
            u32x4 cv = *(const u32x4*)(hpk + word);
            __builtin_nontemporal_store(cv, (u32x4*)(ug + (size_t)row * 64 + 8 * (lane & 7)));
        }

        // ---- next-layer raw-carry GEMM from staged tile ----
        float partial[4] = {0.f, 0.f, 0.f, 0.f};
        {
            int msk = (trow & 7) << 2;
            U4F8 av0, av1;
            av0.u = *(const u32x4*)(hpk + trow * 64 + ((4 * lq) ^ msk));
            av1.u = *(const u32x4*)(hpk + trow * 64 + ((16 + 4 * lq) ^ msk));
            #pragma unroll
            for (int nt = 0; nt < 4; ++nt) {
                int n = nt * 16 + l15;
                f16x8 bh0 = ldfrag(P.BmHn + n * 64 + lq * 8);
                f16x8 bh1 = ldfrag(P.BmHn + n * 64 + 32 + lq * 8);
                f16x8 bl0 = ldfrag(P.BmLn + n * 64 + lq * 8);
                f16x8 bl1 = ldfrag(P.BmLn + n * 64 + 32 + lq * 8);
                f32x4 a4v = {0.f, 0.f, 0.f, 0.f};
                a4v = MFMA(av0.h, bh0, a4v);
                a4v = MFMA(av0.h, bl0, a4v);
                a4v = MFMA(av1.h, bh1, a4v);
                a4v = MFMA(av1.h, bl1, a4v);
                float4 dp = *(const float4*)(P.atabn + n * 64 + 60 - w * 16 - lq * 4);
                partial[nt] += a4v[0] * dp.w + a4v[1] * dp.z + a4v[2] * dp.y + a4v[3] * dp.x;
            }
        }
        #pragma unroll
        for (int nt = 0; nt < 4; ++nt) {
            float v = partial[nt];
            v += __shfl_xor(v, 16);
            v += __shfl_xor(v, 32);
            if (lq == 0) red[w][nt * 16 + l15] = v;
        }
        __syncthreads();                   // barrier 2
        if (w == 0)
            carry[((size_t)b * NCH + c) * 64 + lane] =
                red[0][lane] + red[1][lane] + red[2][lane] + red[3][lane];
    }
}

// ---------- host ----------
extern "C" void kernel_launch(void* const* d_in, const int* in_sizes, int n_in,
                              void* d_out, int out_size, void* d_ws, size_t ws_size,
                              hipStream_t stream)
{
    const float* x   = (const float*)d_in[0];
    const float* Win = (const float*)d_in[1];
    const float* nu  = (const float*)d_in[2];
    const float* ga  = (const float*)d_in[3];
    const float* Bm  = (const float*)d_in[4];
    const float* Cm  = (const float*)d_in[5];
    const float* Dv  = (const float*)d_in[6];
    const float* Wl  = (const float*)d_in[7];
    const float* bl  = (const float*)d_in[8];
    const float* Wo  = (const float*)d_in[9];
    float* out = (float*)d_out;

    char* p = (char*)d_ws;
    f16* ubuf = (f16*)p;            p += (size_t)B_ * T_ * 64 * sizeof(f16);
    float* carry = (float*)p;       p += (size_t)B_ * NCH * 64 * sizeof(float);
    f16* wBmH = (f16*)p;            p += 4 * 4096 * sizeof(f16);
    f16* wBmL = (f16*)p;            p += 4 * 4096 * sizeof(f16);
    f16* wCmH = (f16*)p;            p += 4 * 4096 * sizeof(f16);
    f16* wCmL = (f16*)p;            p += 4 * 4096 * sizeof(f16);
    f16* wWlH = (f16*)p;            p += 4 * 4096 * sizeof(f16);
    float* atab = (float*)p;        p += 4 * 4096 * sizeof(float);
    float* sc = (float*)p;          p += 4 * 320 * sizeof(float);
    f16* dvfH = (f16*)p;            p += 4 * 2048 * sizeof(f16);
    f16* dvfL = (f16*)p;            p += 4 * 2048 * sizeof(f16);
    f16* idf = (f16*)p;             p += 2048 * sizeof(f16);

    dim3 grid(B_ * NCH), blk256(256), gcx(B_ * NCH / 4), gscan(B_);

    prep<<<1, 256, 0, stream>>>(Win, nu, ga, Bm, Cm, Dv, Wl,
                                wBmH, wBmL, wCmH, wCmL, wWlH, atab, sc, dvfH, dvfL, idf);
    carry_x<<<gcx, blk256, 0, stream>>>(x, sc, carry);

    for (int l = 0; l < DEPTH_; ++l) {
        int ln = (l + 1 < DEPTH_) ? l + 1 : l;
        scan_carry<<<gscan, blk256, 0, stream>>>(nu + l * 64, carry);
        LPrep Pr;
        Pr.BmH = wBmH + l * 4096;  Pr.BmL = wBmL + l * 4096;
        Pr.CmH = wCmH + l * 4096;  Pr.CmL = wCmL + l * 4096;
        Pr.WlH = wWlH + l * 4096;
        Pr.av = sc + l * 320;
        Pr.bw = sc + l * 320 + 128; Pr.dwin = sc + l * 320 + 192;
        Pr.win = sc + l * 320 + 256;
        Pr.dvfH = dvfH + l * 2048;  Pr.dvfL = dvfL + l * 2048;  Pr.idf = idf;
        Pr.BmHn = wBmH + ln * 4096; Pr.BmLn = wBmL + ln * 4096;
        Pr.atabn = atab + ln * 4096;
        Pr.blin = bl + l * 64; Pr.Wout = Wo;
        if (l == 0)
            lru_fused<1, 0><<<grid, blk256, 0, stream>>>(x, ubuf, Pr, carry, out);
        else if (l == DEPTH_ - 1)
            lru_fused<0, 1><<<grid, blk256, 0, stream>>>(x, ubuf, Pr, carry, out);
        else
            lru_fused<0, 0><<<grid, blk256, 0, stream>>>(x, ubuf, Pr, carry, out);
    }
}